// Round 1
// baseline (628.480 us; speedup 1.0000x reference)
//
#include <hip/hip_runtime.h>
#include <stdint.h>

#define NLVL 127.0f

__device__ __forceinline__ int dot4(int a, int b, int c) {
#if __has_builtin(__builtin_amdgcn_sdot4)
    return __builtin_amdgcn_sdot4(a, b, c, false);
#else
    int s = c;
    s += ((a << 24) >> 24) * ((b << 24) >> 24);
    s += ((a << 16) >> 24) * ((b << 16) >> 24);
    s += ((a << 8) >> 24) * ((b << 8) >> 24);
    s += (a >> 24) * (b >> 24);
    return s;
#endif
}

// -------- global abs-max reduction (atomicMax on float bits; values >= 0) ----
__global__ __launch_bounds__(256) void amax_abs_kernel(const float* __restrict__ x,
                                                       int n, float* __restrict__ slot) {
    __shared__ float red[256];
    float lm = 0.f;
    for (int i = blockIdx.x * 256 + threadIdx.x; i < n; i += gridDim.x * 256)
        lm = fmaxf(lm, fabsf(x[i]));
    red[threadIdx.x] = lm;
    __syncthreads();
    for (int s = 128; s > 0; s >>= 1) {
        if (threadIdx.x < s) red[threadIdx.x] = fmaxf(red[threadIdx.x], red[threadIdx.x + s]);
        __syncthreads();
    }
    if (threadIdx.x == 0) atomicMax((unsigned int*)slot, __float_as_uint(red[0]));
}

// -------- quantize input x: NCHW fp32 -> NHWC int8 (LDS-tiled transpose) -----
__global__ __launch_bounds__(256) void quant_x_kernel(const float* __restrict__ x,
                                                      signed char* __restrict__ n0,
                                                      const float* __restrict__ scal) {
    __shared__ float tile[32][33];
    const float s = scal[0] / NLVL;
    const int p0 = blockIdx.x * 32, c0 = blockIdx.y * 32, n = blockIdx.z;
    const int tx = threadIdx.x & 31, ty = threadIdx.x >> 5;  // 32 x 8
#pragma unroll
    for (int j = 0; j < 4; j++) {
        const int c = c0 + ty + j * 8;
        const int p = p0 + tx;
        tile[ty + j * 8][tx] = (p < 289) ? x[((size_t)(n * 384 + c)) * 289 + p] : 0.f;
    }
    __syncthreads();
#pragma unroll
    for (int j = 0; j < 4; j++) {
        const int p = p0 + ty + j * 8;
        const int c = c0 + tx;
        if (p < 289) {
            float q = rintf(tile[tx][ty + j * 8] / s);
            q = fminf(fmaxf(q, -128.f), 127.f);
            n0[((size_t)(n * 289 + p)) * 384 + c] = (signed char)q;
        }
    }
}

// -------- fold BN into weights, per-out-channel int8 quant, bias to int ------
// w layout [O][I][KH][KW] -> wq layout [O][kh*KW+kw][I] int8
__global__ __launch_bounds__(256) void prep_w_kernel(
    const float* __restrict__ w, const float* __restrict__ g, const float* __restrict__ b,
    const float* __restrict__ m, const float* __restrict__ v,
    const float* __restrict__ scal, int amax_idx,
    signed char* __restrict__ wq, float* __restrict__ conv_sf, int* __restrict__ bqi,
    int I, int KHW, int KW) {
    const int o = blockIdx.x;
    const int E = I * KHW;
    __shared__ float red[256];
    const float std_ = sqrtf(v[o] + 1e-5f);
    const float fac = g[o] / std_;
    float lm = 0.f;
    for (int e = threadIdx.x; e < E; e += 256)
        lm = fmaxf(lm, fabsf(w[(size_t)o * E + e] * fac));
    red[threadIdx.x] = lm;
    __syncthreads();
    for (int s = 128; s > 0; s >>= 1) {
        if (threadIdx.x < s) red[threadIdx.x] = fmaxf(red[threadIdx.x], red[threadIdx.x + s]);
        __syncthreads();
    }
    const float w_sf = red[0] / NLVL;
    for (int e = threadIdx.x; e < E; e += 256) {
        const float wf = w[(size_t)o * E + e] * fac;
        float q = rintf(wf / w_sf);
        q = fminf(fmaxf(q, -128.f), 127.f);
        const int i = e / KHW;
        const int r = e - i * KHW;  // kh*KW+kw
        wq[((size_t)o * KHW + r) * I + i] = (signed char)q;
    }
    if (threadIdx.x == 0) {
        const float a_sf = scal[amax_idx] / NLVL;
        const float csf = a_sf * w_sf;
        conv_sf[o] = csf;
        const float bf = b[o] - g[o] * m[o] / std_;
        bqi[o] = (int)rintf(bf / csf);
    }
}

// -------- int8 implicit-GEMM conv, fused bias+relu+scale+amax ----------------
// xin: [N][17][17][CIN] int8, wq: [COUT][KH][KW][CIN] int8
// STORE_NCHW=0: yout NHWC fp32 [N][289][COUT]; =1: yout NCHW fp32 with oc_off.
template <int CIN, int COUT, int KH, int KW, int PH, int PW, int STORE_NCHW>
__global__ __launch_bounds__(256) void qconv_kernel(
    const signed char* __restrict__ xin, const signed char* __restrict__ wq,
    const float* __restrict__ conv_sf, const int* __restrict__ bq,
    float* __restrict__ yout, float* __restrict__ amax_slot, int oc_off, int oc_total) {
    constexpr int CINW = CIN / 4;
    constexpr int KC = 16;
    constexpr int NCH = CINW / KC;
    static_assert(CINW % KC == 0, "chunking");
    __shared__ __align__(16) int Xs[KC][68];
    __shared__ __align__(16) int Ws[KC][68];
    __shared__ float red[256];

    const int tid = threadIdx.x;
    const int o_l = (tid & 15) * 4;
    const int p_l = (tid >> 4) * 4;
    const int pos_base = blockIdx.x * 64;
    const int o_base = blockIdx.y * 64;
    const int n = blockIdx.z;

    int acc[16];
#pragma unroll
    for (int i = 0; i < 16; i++) acc[i] = 0;

    const int s_row = tid >> 2;        // 0..63
    const int s_kk = (tid & 3) * 4;    // 0,4,8,12
    const int sp = pos_base + s_row;
    const int sh = sp / 17;
    const int swc = sp - sh * 17;

    for (int kh = 0; kh < KH; kh++) {
        const int ih = sh + kh - PH;
        for (int kw = 0; kw < KW; kw++) {
            const int iw = swc + kw - PW;
            const bool xvalid = (sp < 289) & (ih >= 0) & (ih < 17) & (iw >= 0) & (iw < 17);
            const signed char* xrow = xin + ((size_t)((n * 17 + ih) * 17 + iw)) * CIN;
            const signed char* wrow =
                wq + ((size_t)((o_base + s_row) * KH + kh) * KW + kw) * CIN;
            for (int c0 = 0; c0 < NCH; c0++) {
                int4 xv = make_int4(0, 0, 0, 0);
                if (xvalid) xv = *(const int4*)(xrow + (c0 * KC + s_kk) * 4);
                const int4 wv = *(const int4*)(wrow + (c0 * KC + s_kk) * 4);
                Xs[s_kk + 0][s_row] = xv.x; Xs[s_kk + 1][s_row] = xv.y;
                Xs[s_kk + 2][s_row] = xv.z; Xs[s_kk + 3][s_row] = xv.w;
                Ws[s_kk + 0][s_row] = wv.x; Ws[s_kk + 1][s_row] = wv.y;
                Ws[s_kk + 2][s_row] = wv.z; Ws[s_kk + 3][s_row] = wv.w;
                __syncthreads();
#pragma unroll
                for (int kk = 0; kk < KC; kk++) {
                    const int4 xr = *(const int4*)&Xs[kk][p_l];
                    const int4 wr = *(const int4*)&Ws[kk][o_l];
                    const int xa[4] = {xr.x, xr.y, xr.z, xr.w};
                    const int wa[4] = {wr.x, wr.y, wr.z, wr.w};
#pragma unroll
                    for (int m2 = 0; m2 < 4; m2++)
#pragma unroll
                        for (int j2 = 0; j2 < 4; j2++)
                            acc[m2 * 4 + j2] = dot4(xa[m2], wa[j2], acc[m2 * 4 + j2]);
                }
                __syncthreads();
            }
        }
    }

    float vals[16];
    float lm = 0.f;
#pragma unroll
    for (int m2 = 0; m2 < 4; m2++) {
        const int pos = pos_base + p_l + m2;
#pragma unroll
        for (int j2 = 0; j2 < 4; j2++) {
            const int o = o_base + o_l + j2;
            int t = acc[m2 * 4 + j2] + bq[o];
            t = t > 0 ? t : 0;
            const float v2 = conv_sf[o] * (float)t;
            vals[m2 * 4 + j2] = v2;
            if (pos < 289) lm = fmaxf(lm, v2);
        }
    }
    red[tid] = lm;
    __syncthreads();
    for (int s = 128; s > 0; s >>= 1) {
        if (tid < s) red[tid] = fmaxf(red[tid], red[tid + s]);
        __syncthreads();
    }
    if (tid == 0) atomicMax((unsigned int*)amax_slot, __float_as_uint(red[0]));

    if (STORE_NCHW) {
#pragma unroll
        for (int m2 = 0; m2 < 4; m2++) {
            const int pos = pos_base + p_l + m2;
            if (pos < 289) {
#pragma unroll
                for (int j2 = 0; j2 < 4; j2++) {
                    const int o = o_base + o_l + j2;
                    yout[((size_t)(n * oc_total + oc_off + o)) * 289 + pos] = vals[m2 * 4 + j2];
                }
            }
        }
    } else {
#pragma unroll
        for (int m2 = 0; m2 < 4; m2++) {
            const int pos = pos_base + p_l + m2;
            if (pos < 289) {
                const float4 vv = make_float4(vals[m2 * 4 + 0], vals[m2 * 4 + 1],
                                              vals[m2 * 4 + 2], vals[m2 * 4 + 3]);
                *(float4*)&yout[((size_t)(n * 289 + pos)) * COUT + o_base + o_l] = vv;
            }
        }
    }
}

// -------- requantize fp32 activations -> int8 (same linear layout) ----------
__global__ __launch_bounds__(256) void requant_kernel(const float* __restrict__ f,
                                                      signed char* __restrict__ q,
                                                      const float* __restrict__ scal,
                                                      int idx, int nvec) {
    const float s = scal[idx] / NLVL;
    for (int i = blockIdx.x * 256 + threadIdx.x; i < nvec; i += gridDim.x * 256) {
        const float4 v = ((const float4*)f)[i];
        const int b0 = (int)fminf(fmaxf(rintf(v.x / s), -128.f), 127.f);
        const int b1 = (int)fminf(fmaxf(rintf(v.y / s), -128.f), 127.f);
        const int b2 = (int)fminf(fmaxf(rintf(v.z / s), -128.f), 127.f);
        const int b3 = (int)fminf(fmaxf(rintf(v.w / s), -128.f), 127.f);
        ((unsigned int*)q)[i] =
            (b0 & 0xff) | ((b1 & 0xff) << 8) | ((b2 & 0xff) << 16) | ((b3 & 0xff) << 24);
    }
}

// -------- final in-place requant of d_out ------------------------------------
__global__ __launch_bounds__(256) void final_requant_kernel(float* __restrict__ y,
                                                            const float* __restrict__ scal,
                                                            int idx, int nvec) {
    const float s = scal[idx] / NLVL;
    for (int i = blockIdx.x * 256 + threadIdx.x; i < nvec; i += gridDim.x * 256) {
        float4 v = ((float4*)y)[i];
        v.x = fminf(fmaxf(rintf(v.x / s), -128.f), 127.f) * s;
        v.y = fminf(fmaxf(rintf(v.y / s), -128.f), 127.f) * s;
        v.z = fminf(fmaxf(rintf(v.z / s), -128.f), 127.f) * s;
        v.w = fminf(fmaxf(rintf(v.w / s), -128.f), 127.f) * s;
        ((float4*)y)[i] = v;
    }
}

extern "C" void kernel_launch(void* const* d_in, const int* in_sizes, int n_in,
                              void* d_out, int out_size, void* d_ws, size_t ws_size,
                              hipStream_t stream) {
    const float* x  = (const float*)d_in[0];
    const float* w1 = (const float*)d_in[1];
    const float* g1 = (const float*)d_in[2];
    const float* b1 = (const float*)d_in[3];
    const float* m1 = (const float*)d_in[4];
    const float* v1 = (const float*)d_in[5];
    const float* w2 = (const float*)d_in[6];
    const float* g2 = (const float*)d_in[7];
    const float* b2 = (const float*)d_in[8];
    const float* m2 = (const float*)d_in[9];
    const float* v2 = (const float*)d_in[10];
    const float* w3 = (const float*)d_in[11];
    const float* g3 = (const float*)d_in[12];
    const float* b3 = (const float*)d_in[13];
    const float* m3 = (const float*)d_in[14];
    const float* v3 = (const float*)d_in[15];
    const float* w4 = (const float*)d_in[16];
    const float* g4 = (const float*)d_in[17];
    const float* b4 = (const float*)d_in[18];
    const float* m4 = (const float*)d_in[19];
    const float* v4 = (const float*)d_in[20];
    float* out = (float*)d_out;
    char* ws = (char*)d_ws;

    size_t off = 0;
    auto take = [&](size_t bytes) {
        char* p = ws + off;
        off = (off + bytes + 255) & ~(size_t)255;
        return p;
    };
    float* scal = (float*)take(64);                                   // amax slots
    signed char* wq1 = (signed char*)take((size_t)448 * 384);
    float* sf1 = (float*)take(448 * 4);
    int* bq1 = (int*)take(448 * 4);
    signed char* wq2 = (signed char*)take((size_t)384 * 9 * 448);
    float* sf2 = (float*)take(384 * 4);
    int* bq2 = (int*)take(384 * 4);
    signed char* wq3 = (signed char*)take((size_t)384 * 3 * 384);
    float* sf3 = (float*)take(384 * 4);
    int* bq3 = (int*)take(384 * 4);
    signed char* wq4 = (signed char*)take((size_t)384 * 3 * 384);
    float* sf4 = (float*)take(384 * 4);
    int* bq4 = (int*)take(384 * 4);
    signed char* n0 = (signed char*)take((size_t)64 * 289 * 384);     // int8 NHWC
    signed char* q1 = (signed char*)take((size_t)64 * 289 * 448);
    signed char* q2 = (signed char*)take((size_t)64 * 289 * 384);
    float* fbuf = (float*)take((size_t)64 * 289 * 448 * 4);           // fp32 pre-requant

    hipMemsetAsync(scal, 0, 64, stream);

    // stage 0: quantize input
    amax_abs_kernel<<<1024, 256, 0, stream>>>(x, 64 * 384 * 289, scal + 0);
    quant_x_kernel<<<dim3(10, 12, 64), 256, 0, stream>>>(x, n0, scal);

    // conv1: 1x1, 384->448
    prep_w_kernel<<<448, 256, 0, stream>>>(w1, g1, b1, m1, v1, scal, 0, wq1, sf1, bq1, 384, 1, 1);
    qconv_kernel<384, 448, 1, 1, 0, 0, 0>
        <<<dim3(5, 7, 64), 256, 0, stream>>>(n0, wq1, sf1, bq1, fbuf, scal + 1, 0, 0);
    requant_kernel<<<2048, 256, 0, stream>>>(fbuf, q1, scal, 1, 64 * 289 * 448 / 4);

    // conv2: 3x3 pad 1, 448->384
    prep_w_kernel<<<384, 256, 0, stream>>>(w2, g2, b2, m2, v2, scal, 1, wq2, sf2, bq2, 448, 9, 3);
    qconv_kernel<448, 384, 3, 3, 1, 1, 0>
        <<<dim3(5, 6, 64), 256, 0, stream>>>(q1, wq2, sf2, bq2, fbuf, scal + 2, 0, 0);
    requant_kernel<<<2048, 256, 0, stream>>>(fbuf, q2, scal, 2, 64 * 289 * 384 / 4);

    // branches: conv3 (1x3, pad w), conv4 (3x1, pad h) -> fp32 into d_out (concat)
    prep_w_kernel<<<384, 256, 0, stream>>>(w3, g3, b3, m3, v3, scal, 2, wq3, sf3, bq3, 384, 3, 3);
    prep_w_kernel<<<384, 256, 0, stream>>>(w4, g4, b4, m4, v4, scal, 2, wq4, sf4, bq4, 384, 3, 1);
    qconv_kernel<384, 384, 1, 3, 0, 1, 1>
        <<<dim3(5, 6, 64), 256, 0, stream>>>(q2, wq3, sf3, bq3, out, scal + 3, 0, 768);
    qconv_kernel<384, 384, 3, 1, 1, 0, 1>
        <<<dim3(5, 6, 64), 256, 0, stream>>>(q2, wq4, sf4, bq4, out, scal + 3, 384, 768);

    // final: requant concat in place
    final_requant_kernel<<<2048, 256, 0, stream>>>(out, scal, 3, 64 * 768 * 289 / 4);
}

// Round 3
// 320.708 us; speedup vs baseline: 1.9597x; 1.9597x over previous
//
#include <hip/hip_runtime.h>
#include <stdint.h>

#define NLVL 127.0f

typedef int v4i __attribute__((ext_vector_type(4)));
typedef int v16i __attribute__((ext_vector_type(16)));

__device__ __forceinline__ void gload_lds16(const void* g, void* l) {
    __builtin_amdgcn_global_load_lds((const __attribute__((address_space(1))) void*)g,
                                     (__attribute__((address_space(3))) void*)l, 16, 0, 0);
}

// -------- global abs-max reduction (atomicMax on float bits; values >= 0) ----
__global__ __launch_bounds__(256) void amax_abs_kernel(const float* __restrict__ x,
                                                       int n, float* __restrict__ slot) {
    __shared__ float red[256];
    float lm = 0.f;
    for (int i = blockIdx.x * 256 + threadIdx.x; i < n; i += gridDim.x * 256)
        lm = fmaxf(lm, fabsf(x[i]));
    red[threadIdx.x] = lm;
    __syncthreads();
    for (int s = 128; s > 0; s >>= 1) {
        if (threadIdx.x < s) red[threadIdx.x] = fmaxf(red[threadIdx.x], red[threadIdx.x + s]);
        __syncthreads();
    }
    if (threadIdx.x == 0) atomicMax((unsigned int*)slot, __float_as_uint(red[0]));
}

// -------- quantize input x: NCHW fp32 -> NHWC int8 (LDS-tiled transpose) -----
__global__ __launch_bounds__(256) void quant_x_kernel(const float* __restrict__ x,
                                                      signed char* __restrict__ n0,
                                                      const float* __restrict__ scal) {
    __shared__ float tile[32][33];
    const float s = scal[0] / NLVL;
    const int p0 = blockIdx.x * 32, c0 = blockIdx.y * 32, n = blockIdx.z;
    const int tx = threadIdx.x & 31, ty = threadIdx.x >> 5;  // 32 x 8
#pragma unroll
    for (int j = 0; j < 4; j++) {
        const int c = c0 + ty + j * 8;
        const int p = p0 + tx;
        tile[ty + j * 8][tx] = (p < 289) ? x[((size_t)(n * 384 + c)) * 289 + p] : 0.f;
    }
    __syncthreads();
#pragma unroll
    for (int j = 0; j < 4; j++) {
        const int p = p0 + ty + j * 8;
        const int c = c0 + tx;
        if (p < 289) {
            float q = rintf(tile[tx][ty + j * 8] / s);
            q = fminf(fmaxf(q, -128.f), 127.f);
            n0[((size_t)(n * 289 + p)) * 384 + c] = (signed char)q;
        }
    }
}

// -------- fold BN into weights, per-out-channel int8 quant, bias to int ------
// w [O][I][KH][KW] -> wstg [tap][kc][khalf][OCP][16] int8 (MFMA-stage layout)
__global__ __launch_bounds__(256) void prep_w_kernel(
    const float* __restrict__ w, const float* __restrict__ g, const float* __restrict__ b,
    const float* __restrict__ m, const float* __restrict__ v,
    const float* __restrict__ scal, int amax_idx,
    signed char* __restrict__ wstg, float* __restrict__ conv_sf, int* __restrict__ bqi,
    int I, int KHW, int OCP) {
    const int o = blockIdx.x;
    const int E = I * KHW;
    const int KCN = I >> 5;
    __shared__ float red[256];
    const float std_ = sqrtf(v[o] + 1e-5f);
    const float fac = g[o] / std_;
    float lm = 0.f;
    for (int e = threadIdx.x; e < E; e += 256)
        lm = fmaxf(lm, fabsf(w[(size_t)o * E + e] * fac));
    red[threadIdx.x] = lm;
    __syncthreads();
    for (int s = 128; s > 0; s >>= 1) {
        if (threadIdx.x < s) red[threadIdx.x] = fmaxf(red[threadIdx.x], red[threadIdx.x + s]);
        __syncthreads();
    }
    const float w_sf = red[0] / NLVL;
    for (int e = threadIdx.x; e < E; e += 256) {
        const float wf = w[(size_t)o * E + e] * fac;
        float q = rintf(wf / w_sf);
        q = fminf(fmaxf(q, -128.f), 127.f);
        const int i = e / KHW;          // cin
        const int r = e - i * KHW;      // tap = kh*KW+kw
        const int kc = i >> 5, kh2 = (i >> 4) & 1, j = i & 15;
        wstg[((((size_t)r * KCN + kc) * 2 + kh2) * OCP + o) * 16 + j] = (signed char)q;
    }
    if (threadIdx.x == 0) {
        const float a_sf = scal[amax_idx] / NLVL;
        const float csf = a_sf * w_sf;
        conv_sf[o] = csf;
        const float bf = b[o] - g[o] * m[o] / std_;
        bqi[o] = (int)rintf(bf / csf);
    }
}

// -------- int8 MFMA implicit-GEMM conv, fused bias+relu+scale+amax -----------
// xin: [N*289][CIN] int8 NHWC; wstg packed as above.
// STORE_NCHW=0: yout NHWC fp32 [pos][COUT]; =1: NCHW fp32 with oc_off.
template <int CIN, int COUT, int OCP, int KH, int KW, int PH, int PW, int STORE_NCHW>
__global__ __launch_bounds__(256) void qconv_mfma(
    const signed char* __restrict__ xin, const signed char* __restrict__ wstg,
    const float* __restrict__ conv_sf, const int* __restrict__ bqv,
    float* __restrict__ yout, float* __restrict__ amax_slot,
    const signed char* __restrict__ zero16, int oc_off, int oc_total) {
    constexpr int KCN = CIN / 32;
    constexpr int KHW = KH * KW;
    constexpr int NKT = KHW * KCN;
    constexpr int TOTP = 64 * 289;
    __shared__ __align__(16) signed char lds[2][8192];  // per buf: A[2][128][16] | B[2][128][16]
    __shared__ float red[256];

    const int tid = threadIdx.x;
    const int lane = tid & 63;
    const int wid = tid >> 6;
    const int l31 = lane & 31;
    const int lh = lane >> 5;

    // staging identity: row/col = tid&127, khalf = tid>>7
    const int srow = tid & 127;
    const int skh = tid >> 7;
    const int p_blk = blockIdx.x * 128;
    const int myp = p_blk + srow;
    const bool rowok = myp < TOTP;
    const int pc = rowok ? myp : 0;
    const int myn = pc / 289;
    const int myhw = pc - myn * 289;
    const int myh = myhw / 17;
    const int myw = myhw - myh * 17;
    const signed char* arow0 = xin + ((size_t)myn * 289) * CIN + skh * 16;
    const size_t bsrc_oc = (size_t)(blockIdx.y * 128 + srow);

    auto stage = [&](int cbuf, int kt) {
        const int tap = kt / KCN;
        const int kc = kt - tap * KCN;
        const int kh = tap / KW;
        const int kw = tap - kh * KW;
        const int ih = myh + kh - PH;
        const int iw = myw + kw - PW;
        const bool ok = rowok & ((unsigned)ih < 17u) & ((unsigned)iw < 17u);
        const signed char* asrc =
            ok ? (arow0 + ((size_t)(ih * 17 + iw)) * CIN + kc * 32) : zero16;
        const signed char* bsrc =
            wstg + ((((size_t)tap * KCN + kc) * 2 + skh) * OCP + bsrc_oc) * 16;
        gload_lds16(asrc, &lds[cbuf][wid * 1024]);
        gload_lds16(bsrc, &lds[cbuf][4096 + wid * 1024]);
    };

    v16i acc[2][2] = {};

    stage(0, 0);
    __syncthreads();
    int cur = 0;
    for (int kt = 0; kt < NKT; ++kt) {
        if (kt + 1 < NKT) stage(cur ^ 1, kt + 1);
        const signed char* Abase = &lds[cur][0];
        const signed char* Bbase = &lds[cur][4096];
        v4i af[2], bf[2];
#pragma unroll
        for (int it = 0; it < 2; ++it) {
            const int arow = (wid >> 1) * 64 + it * 32 + l31;
            af[it] = *(const v4i*)(Abase + (lh * 128 + arow) * 16);
        }
#pragma unroll
        for (int jt = 0; jt < 2; ++jt) {
            const int bcol = (wid & 1) * 64 + jt * 32 + l31;
            bf[jt] = *(const v4i*)(Bbase + (lh * 128 + bcol) * 16);
        }
#pragma unroll
        for (int it = 0; it < 2; ++it)
#pragma unroll
            for (int jt = 0; jt < 2; ++jt)
                acc[it][jt] = __builtin_amdgcn_mfma_i32_32x32x32_i8(af[it], bf[jt], acc[it][jt], 0, 0, 0);
        __syncthreads();
        cur ^= 1;
    }

    // epilogue: bias + relu + per-channel scale, amax, store
    float csf[2];
    int bb[2], ocv[2];
    bool ocok[2];
#pragma unroll
    for (int jt = 0; jt < 2; ++jt) {
        const int oc = blockIdx.y * 128 + (wid & 1) * 64 + jt * 32 + l31;
        ocv[jt] = oc;
        ocok[jt] = oc < COUT;
        csf[jt] = ocok[jt] ? conv_sf[oc] : 0.f;
        bb[jt] = ocok[jt] ? bqv[oc] : 0;
    }
    float lm = 0.f;
#pragma unroll
    for (int it = 0; it < 2; ++it) {
#pragma unroll
        for (int reg = 0; reg < 16; ++reg) {
            const int prow = p_blk + (wid >> 1) * 64 + it * 32 + (reg & 3) + 8 * (reg >> 2) + 4 * lh;
            const bool pok = prow < TOTP;
#pragma unroll
            for (int jt = 0; jt < 2; ++jt) {
                int t = acc[it][jt][reg] + bb[jt];
                t = t > 0 ? t : 0;
                const float v2 = csf[jt] * (float)t;
                if (pok & ocok[jt]) {
                    lm = fmaxf(lm, v2);
                    if (STORE_NCHW) {
                        const int n = prow / 289;
                        const int hw = prow - n * 289;
                        yout[((size_t)(n * oc_total + oc_off + ocv[jt])) * 289 + hw] = v2;
                    } else {
                        yout[(size_t)prow * COUT + ocv[jt]] = v2;
                    }
                }
            }
        }
    }
    red[tid] = lm;
    __syncthreads();
    for (int s = 128; s > 0; s >>= 1) {
        if (tid < s) red[tid] = fmaxf(red[tid], red[tid + s]);
        __syncthreads();
    }
    if (tid == 0) atomicMax((unsigned int*)amax_slot, __float_as_uint(red[0]));
}

// -------- requantize fp32 activations -> int8 (same linear layout) ----------
__global__ __launch_bounds__(256) void requant_kernel(const float* __restrict__ f,
                                                      signed char* __restrict__ q,
                                                      const float* __restrict__ scal,
                                                      int idx, int nvec) {
    const float s = scal[idx] / NLVL;
    for (int i = blockIdx.x * 256 + threadIdx.x; i < nvec; i += gridDim.x * 256) {
        const float4 v = ((const float4*)f)[i];
        const int b0 = (int)fminf(fmaxf(rintf(v.x / s), -128.f), 127.f);
        const int b1 = (int)fminf(fmaxf(rintf(v.y / s), -128.f), 127.f);
        const int b2 = (int)fminf(fmaxf(rintf(v.z / s), -128.f), 127.f);
        const int b3 = (int)fminf(fmaxf(rintf(v.w / s), -128.f), 127.f);
        ((unsigned int*)q)[i] =
            (b0 & 0xff) | ((b1 & 0xff) << 8) | ((b2 & 0xff) << 16) | ((b3 & 0xff) << 24);
    }
}

// -------- final in-place requant of d_out ------------------------------------
__global__ __launch_bounds__(256) void final_requant_kernel(float* __restrict__ y,
                                                            const float* __restrict__ scal,
                                                            int idx, int nvec) {
    const float s = scal[idx] / NLVL;
    for (int i = blockIdx.x * 256 + threadIdx.x; i < nvec; i += gridDim.x * 256) {
        float4 v = ((float4*)y)[i];
        v.x = fminf(fmaxf(rintf(v.x / s), -128.f), 127.f) * s;
        v.y = fminf(fmaxf(rintf(v.y / s), -128.f), 127.f) * s;
        v.z = fminf(fmaxf(rintf(v.z / s), -128.f), 127.f) * s;
        v.w = fminf(fmaxf(rintf(v.w / s), -128.f), 127.f) * s;
        ((float4*)y)[i] = v;
    }
}

extern "C" void kernel_launch(void* const* d_in, const int* in_sizes, int n_in,
                              void* d_out, int out_size, void* d_ws, size_t ws_size,
                              hipStream_t stream) {
    const float* x  = (const float*)d_in[0];
    const float* w1 = (const float*)d_in[1];
    const float* g1 = (const float*)d_in[2];
    const float* b1 = (const float*)d_in[3];
    const float* m1 = (const float*)d_in[4];
    const float* v1 = (const float*)d_in[5];
    const float* w2 = (const float*)d_in[6];
    const float* g2 = (const float*)d_in[7];
    const float* b2 = (const float*)d_in[8];
    const float* m2 = (const float*)d_in[9];
    const float* v2 = (const float*)d_in[10];
    const float* w3 = (const float*)d_in[11];
    const float* g3 = (const float*)d_in[12];
    const float* b3 = (const float*)d_in[13];
    const float* m3 = (const float*)d_in[14];
    const float* v3 = (const float*)d_in[15];
    const float* w4 = (const float*)d_in[16];
    const float* g4 = (const float*)d_in[17];
    const float* b4 = (const float*)d_in[18];
    const float* m4 = (const float*)d_in[19];
    const float* v4 = (const float*)d_in[20];
    float* out = (float*)d_out;
    char* ws = (char*)d_ws;

    size_t off = 0;
    auto take = [&](size_t bytes) {
        char* p = ws + off;
        off = (off + bytes + 255) & ~(size_t)255;
        return p;
    };
    float* scal = (float*)take(64);  // amax slots 0..3; bytes 32..47 = zero16
    const signed char* zero16 = (const signed char*)(scal + 8);
    signed char* wstg1 = (signed char*)take((size_t)12 * 2 * 512 * 16);
    float* sf1 = (float*)take(448 * 4);
    int* bq1 = (int*)take(448 * 4);
    signed char* wstg2 = (signed char*)take((size_t)9 * 14 * 2 * 384 * 16);
    float* sf2 = (float*)take(384 * 4);
    int* bq2 = (int*)take(384 * 4);
    signed char* wstg3 = (signed char*)take((size_t)3 * 12 * 2 * 384 * 16);
    float* sf3 = (float*)take(384 * 4);
    int* bq3 = (int*)take(384 * 4);
    signed char* wstg4 = (signed char*)take((size_t)3 * 12 * 2 * 384 * 16);
    float* sf4 = (float*)take(384 * 4);
    int* bq4 = (int*)take(384 * 4);
    signed char* n0 = (signed char*)take((size_t)64 * 289 * 384);  // int8 NHWC
    signed char* q1 = (signed char*)take((size_t)64 * 289 * 448);
    signed char* q2 = (signed char*)take((size_t)64 * 289 * 384);
    float* fbuf = (float*)take((size_t)64 * 289 * 448 * 4);        // fp32 pre-requant

    hipMemsetAsync(scal, 0, 64, stream);

    // stage 0: quantize input
    amax_abs_kernel<<<1024, 256, 0, stream>>>(x, 64 * 384 * 289, scal + 0);
    quant_x_kernel<<<dim3(10, 12, 64), 256, 0, stream>>>(x, n0, scal);

    // conv1: 1x1, 384->448 (OC padded to 512)
    prep_w_kernel<<<448, 256, 0, stream>>>(w1, g1, b1, m1, v1, scal, 0, wstg1, sf1, bq1, 384, 1, 512);
    qconv_mfma<384, 448, 512, 1, 1, 0, 0, 0>
        <<<dim3(145, 4), 256, 0, stream>>>(n0, wstg1, sf1, bq1, fbuf, scal + 1, zero16, 0, 0);
    requant_kernel<<<2048, 256, 0, stream>>>(fbuf, q1, scal, 1, 64 * 289 * 448 / 4);

    // conv2: 3x3 pad 1, 448->384
    prep_w_kernel<<<384, 256, 0, stream>>>(w2, g2, b2, m2, v2, scal, 1, wstg2, sf2, bq2, 448, 9, 384);
    qconv_mfma<448, 384, 384, 3, 3, 1, 1, 0>
        <<<dim3(145, 3), 256, 0, stream>>>(q1, wstg2, sf2, bq2, fbuf, scal + 2, zero16, 0, 0);
    requant_kernel<<<2048, 256, 0, stream>>>(fbuf, q2, scal, 2, 64 * 289 * 384 / 4);

    // branches: conv3 (1x3, pad w), conv4 (3x1, pad h) -> fp32 NCHW into d_out
    prep_w_kernel<<<384, 256, 0, stream>>>(w3, g3, b3, m3, v3, scal, 2, wstg3, sf3, bq3, 384, 3, 384);
    prep_w_kernel<<<384, 256, 0, stream>>>(w4, g4, b4, m4, v4, scal, 2, wstg4, sf4, bq4, 384, 3, 384);
    qconv_mfma<384, 384, 384, 1, 3, 0, 1, 1>
        <<<dim3(145, 3), 256, 0, stream>>>(q2, wstg3, sf3, bq3, out, scal + 3, zero16, 0, 768);
    qconv_mfma<384, 384, 384, 3, 1, 1, 0, 1>
        <<<dim3(145, 3), 256, 0, stream>>>(q2, wstg4, sf4, bq4, out, scal + 3, zero16, 384, 768);

    // final: requant concat in place
    final_requant_kernel<<<2048, 256, 0, stream>>>(out, scal, 3, 64 * 768 * 289 / 4);
}

// Round 4
// 294.081 us; speedup vs baseline: 2.1371x; 1.0905x over previous
//
#include <hip/hip_runtime.h>
#include <stdint.h>

#define NLVL 127.0f

typedef int v4i __attribute__((ext_vector_type(4)));
typedef int v16i __attribute__((ext_vector_type(16)));

__device__ __forceinline__ void gload_lds16(const void* g, void* l) {
    __builtin_amdgcn_global_load_lds((const __attribute__((address_space(1))) void*)g,
                                     (__attribute__((address_space(3))) void*)l, 16, 0, 0);
}

// -------- global abs-max reduction (atomicMax on float bits; values >= 0) ----
__global__ __launch_bounds__(256) void amax_abs_kernel(const float* __restrict__ x,
                                                       int n, float* __restrict__ slot) {
    __shared__ float red[256];
    float lm = 0.f;
    for (int i = blockIdx.x * 256 + threadIdx.x; i < n; i += gridDim.x * 256)
        lm = fmaxf(lm, fabsf(x[i]));
    red[threadIdx.x] = lm;
    __syncthreads();
    for (int s = 128; s > 0; s >>= 1) {
        if (threadIdx.x < s) red[threadIdx.x] = fmaxf(red[threadIdx.x], red[threadIdx.x + s]);
        __syncthreads();
    }
    if (threadIdx.x == 0) atomicMax((unsigned int*)slot, __float_as_uint(red[0]));
}

// -------- quantize input x: NCHW fp32 -> NHWC int8 (LDS-tiled transpose) -----
__global__ __launch_bounds__(256) void quant_x_kernel(const float* __restrict__ x,
                                                      signed char* __restrict__ n0,
                                                      const float* __restrict__ scal) {
    __shared__ float tile[32][33];
    const float s = scal[0] / NLVL;
    const int p0 = blockIdx.x * 32, c0 = blockIdx.y * 32, n = blockIdx.z;
    const int tx = threadIdx.x & 31, ty = threadIdx.x >> 5;  // 32 x 8
#pragma unroll
    for (int j = 0; j < 4; j++) {
        const int c = c0 + ty + j * 8;
        const int p = p0 + tx;
        tile[ty + j * 8][tx] = (p < 289) ? x[((size_t)(n * 384 + c)) * 289 + p] : 0.f;
    }
    __syncthreads();
#pragma unroll
    for (int j = 0; j < 4; j++) {
        const int p = p0 + ty + j * 8;
        const int c = c0 + tx;
        if (p < 289) {
            float q = rintf(tile[tx][ty + j * 8] / s);
            q = fminf(fmaxf(q, -128.f), 127.f);
            n0[((size_t)(n * 289 + p)) * 384 + c] = (signed char)q;
        }
    }
}

// -------- fold BN into weights, per-out-channel int8 quant, bias to int ------
// w [O][I][KH][KW] -> wstg [tap][kcn][j=8][OCP][16] int8 (128-ch chunk layout)
__global__ __launch_bounds__(256) void prep_w_kernel(
    const float* __restrict__ w, const float* __restrict__ g, const float* __restrict__ b,
    const float* __restrict__ m, const float* __restrict__ v,
    const float* __restrict__ scal, int amax_idx,
    signed char* __restrict__ wstg, float* __restrict__ conv_sf, int* __restrict__ bqi,
    int I, int KHW, int OCP, int KCN) {
    const int o = blockIdx.x;
    const int E = I * KHW;
    __shared__ float red[256];
    const float std_ = sqrtf(v[o] + 1e-5f);
    const float fac = g[o] / std_;
    float lm = 0.f;
    for (int e = threadIdx.x; e < E; e += 256)
        lm = fmaxf(lm, fabsf(w[(size_t)o * E + e] * fac));
    red[threadIdx.x] = lm;
    __syncthreads();
    for (int s = 128; s > 0; s >>= 1) {
        if (threadIdx.x < s) red[threadIdx.x] = fmaxf(red[threadIdx.x], red[threadIdx.x + s]);
        __syncthreads();
    }
    const float w_sf = red[0] / NLVL;
    for (int e = threadIdx.x; e < E; e += 256) {
        const float wf = w[(size_t)o * E + e] * fac;
        float q = rintf(wf / w_sf);
        q = fminf(fmaxf(q, -128.f), 127.f);
        const int i = e / KHW;          // cin
        const int r = e - i * KHW;      // tap = kh*KW+kw
        const int kcn = i >> 7, j = (i >> 4) & 7, byte = i & 15;
        wstg[((((size_t)r * KCN + kcn) * 8 + j) * OCP + o) * 16 + byte] = (signed char)q;
    }
    if (threadIdx.x == 0) {
        const float a_sf = scal[amax_idx] / NLVL;
        const float csf = a_sf * w_sf;
        conv_sf[o] = csf;
        const float bf = b[o] - g[o] * m[o] / std_;
        bqi[o] = (int)rintf(bf / csf);
    }
}

// -------- int8 MFMA implicit-GEMM conv, K=128 chunks, dbuf, fused epilogue ---
// xin: [N*289][CINP] int8 NHWC; wstg packed as above.
// STORE_NCHW=0: yout NHWC fp32 [pos][OCP] (pads stored as 0); =1: NCHW + oc_off.
template <int CINP, int COUT, int OCP, int KH, int KW, int PH, int PW, int STORE_NCHW>
__global__ __launch_bounds__(256) void qconv_mfma(
    const signed char* __restrict__ xin, const signed char* __restrict__ wstg,
    const float* __restrict__ conv_sf, const int* __restrict__ bqv,
    float* __restrict__ yout, float* __restrict__ amax_slot,
    const signed char* __restrict__ zero16, int oc_off, int oc_total) {
    constexpr int KCN = CINP / 128;
    constexpr int KHW = KH * KW;
    constexpr int NKT = KHW * KCN;
    constexpr int TOTP = 64 * 289;
    // per buf: A [j=8][128 pos][16B] (16KB) | B [j=8][128 oc][16B] (16KB)
    __shared__ __align__(16) signed char lds[2][32768];

    const int tid = threadIdx.x;
    const int lane = tid & 63;
    const int wid = tid >> 6;
    const int l31 = lane & 31;
    const int lh = lane >> 5;

    const int srow = tid & 127;   // pos-row / oc-col this thread stages
    const int j0 = tid >> 7;      // 0/1
    const int p_blk = blockIdx.x * 128;
    const int myp = p_blk + srow;
    const bool rowok = myp < TOTP;
    const int pc = rowok ? myp : 0;
    const int myn = pc / 289;
    const int myhw = pc - myn * 289;
    const int myh = myhw / 17;
    const int myw = myhw - myh * 17;
    const int oc_blk = blockIdx.y * 128;

    auto stage = [&](int cbuf, int kt) {
        const int tap = kt / KCN;
        const int kc = kt - tap * KCN;
        const int kh = tap / KW;
        const int kw = tap - kh * KW;
        const int ih = myh + kh - PH;
        const int iw = myw + kw - PW;
        const bool ok = rowok & ((unsigned)ih < 17u) & ((unsigned)iw < 17u);
        const signed char* abase =
            xin + ((size_t)(myn * 289 + ih * 17 + iw)) * CINP + kc * 128 + j0 * 16;
        const signed char* bbase =
            wstg + (((size_t)(tap * KCN + kc) * 8 + j0) * OCP + oc_blk + srow) * 16;
        signed char* Al = &lds[cbuf][0];
        signed char* Bl = &lds[cbuf][16384];
#pragma unroll
        for (int r = 0; r < 4; ++r) {
            gload_lds16(ok ? (abase + 2 * r * 16) : zero16, Al + (wid * 64 + 256 * r) * 16);
            gload_lds16(bbase + (size_t)(2 * r) * OCP * 16, Bl + (wid * 64 + 256 * r) * 16);
        }
    };

    v16i acc[2][2] = {};

    stage(0, 0);
    __syncthreads();
    int cur = 0;
    for (int kt = 0; kt < NKT; ++kt) {
        if (kt + 1 < NKT) stage(cur ^ 1, kt + 1);
        const signed char* Al = &lds[cur][0];
        const signed char* Bl = &lds[cur][16384];
#pragma unroll
        for (int ks = 0; ks < 4; ++ks) {
            v4i af[2], bf[2];
#pragma unroll
            for (int it = 0; it < 2; ++it)
                af[it] = *(const v4i*)(Al + (((ks * 2 + lh) * 128) + (wid >> 1) * 64 + it * 32 + l31) * 16);
#pragma unroll
            for (int jt = 0; jt < 2; ++jt)
                bf[jt] = *(const v4i*)(Bl + (((ks * 2 + lh) * 128) + (wid & 1) * 64 + jt * 32 + l31) * 16);
#pragma unroll
            for (int it = 0; it < 2; ++it)
#pragma unroll
                for (int jt = 0; jt < 2; ++jt)
                    acc[it][jt] =
                        __builtin_amdgcn_mfma_i32_32x32x32_i8(af[it], bf[jt], acc[it][jt], 0, 0, 0);
        }
        __syncthreads();
        cur ^= 1;
    }

    // epilogue: bias + relu + per-channel scale, amax, store
    float csf[2];
    int bb[2], ocv[2];
#pragma unroll
    for (int jt = 0; jt < 2; ++jt) {
        const int oc = oc_blk + (wid & 1) * 64 + jt * 32 + l31;
        ocv[jt] = oc;
        const bool real = oc < COUT;
        csf[jt] = real ? conv_sf[oc] : 0.f;
        bb[jt] = real ? bqv[oc] : 0;
    }
    float lm = 0.f;
#pragma unroll
    for (int it = 0; it < 2; ++it) {
#pragma unroll
        for (int reg = 0; reg < 16; ++reg) {
            const int prow = p_blk + (wid >> 1) * 64 + it * 32 + (reg & 3) + 8 * (reg >> 2) + 4 * lh;
            const bool pok = prow < TOTP;
#pragma unroll
            for (int jt = 0; jt < 2; ++jt) {
                int t = acc[it][jt][reg] + bb[jt];
                t = t > 0 ? t : 0;
                const float v2 = csf[jt] * (float)t;
                if (pok) {
                    lm = fmaxf(lm, v2);
                    if (STORE_NCHW) {
                        if (ocv[jt] < COUT) {
                            const int n = prow / 289;
                            const int hw = prow - n * 289;
                            yout[((size_t)(n * oc_total + oc_off + ocv[jt])) * 289 + hw] = v2;
                        }
                    } else {
                        yout[(size_t)prow * OCP + ocv[jt]] = v2;  // pads store 0
                    }
                }
            }
        }
    }
    float* red = (float*)&lds[0][0];
    red[tid] = lm;
    __syncthreads();
    for (int s = 128; s > 0; s >>= 1) {
        if (tid < s) red[tid] = fmaxf(red[tid], red[tid + s]);
        __syncthreads();
    }
    if (tid == 0) atomicMax((unsigned int*)amax_slot, __float_as_uint(red[0]));
}

// -------- requantize fp32 activations -> int8 (same linear layout) ----------
__global__ __launch_bounds__(256) void requant_kernel(const float* __restrict__ f,
                                                      signed char* __restrict__ q,
                                                      const float* __restrict__ scal,
                                                      int idx, int nvec) {
    const float s = scal[idx] / NLVL;
    for (int i = blockIdx.x * 256 + threadIdx.x; i < nvec; i += gridDim.x * 256) {
        const float4 v = ((const float4*)f)[i];
        const int b0 = (int)fminf(fmaxf(rintf(v.x / s), -128.f), 127.f);
        const int b1 = (int)fminf(fmaxf(rintf(v.y / s), -128.f), 127.f);
        const int b2 = (int)fminf(fmaxf(rintf(v.z / s), -128.f), 127.f);
        const int b3 = (int)fminf(fmaxf(rintf(v.w / s), -128.f), 127.f);
        ((unsigned int*)q)[i] =
            (b0 & 0xff) | ((b1 & 0xff) << 8) | ((b2 & 0xff) << 16) | ((b3 & 0xff) << 24);
    }
}

// -------- final in-place requant of d_out ------------------------------------
__global__ __launch_bounds__(256) void final_requant_kernel(float* __restrict__ y,
                                                            const float* __restrict__ scal,
                                                            int idx, int nvec) {
    const float s = scal[idx] / NLVL;
    for (int i = blockIdx.x * 256 + threadIdx.x; i < nvec; i += gridDim.x * 256) {
        float4 v = ((float4*)y)[i];
        v.x = fminf(fmaxf(rintf(v.x / s), -128.f), 127.f) * s;
        v.y = fminf(fmaxf(rintf(v.y / s), -128.f), 127.f) * s;
        v.z = fminf(fmaxf(rintf(v.z / s), -128.f), 127.f) * s;
        v.w = fminf(fmaxf(rintf(v.w / s), -128.f), 127.f) * s;
        ((float4*)y)[i] = v;
    }
}

extern "C" void kernel_launch(void* const* d_in, const int* in_sizes, int n_in,
                              void* d_out, int out_size, void* d_ws, size_t ws_size,
                              hipStream_t stream) {
    const float* x  = (const float*)d_in[0];
    const float* w1 = (const float*)d_in[1];
    const float* g1 = (const float*)d_in[2];
    const float* b1 = (const float*)d_in[3];
    const float* m1 = (const float*)d_in[4];
    const float* v1 = (const float*)d_in[5];
    const float* w2 = (const float*)d_in[6];
    const float* g2 = (const float*)d_in[7];
    const float* b2 = (const float*)d_in[8];
    const float* m2 = (const float*)d_in[9];
    const float* v2 = (const float*)d_in[10];
    const float* w3 = (const float*)d_in[11];
    const float* g3 = (const float*)d_in[12];
    const float* b3 = (const float*)d_in[13];
    const float* m3 = (const float*)d_in[14];
    const float* v3 = (const float*)d_in[15];
    const float* w4 = (const float*)d_in[16];
    const float* g4 = (const float*)d_in[17];
    const float* b4 = (const float*)d_in[18];
    const float* m4 = (const float*)d_in[19];
    const float* v4 = (const float*)d_in[20];
    float* out = (float*)d_out;
    char* ws = (char*)d_ws;

    size_t off = 0;
    auto take = [&](size_t bytes) {
        char* p = ws + off;
        off = (off + bytes + 255) & ~(size_t)255;
        return p;
    };
    float* scal = (float*)take(64);  // amax slots 0..3; bytes 32..47 = zero16
    const signed char* zero16 = (const signed char*)(scal + 8);
    signed char* wstg1 = (signed char*)take((size_t)1 * 3 * 8 * 512 * 16);
    float* sf1 = (float*)take(448 * 4);
    int* bq1 = (int*)take(448 * 4);
    signed char* wstg2 = (signed char*)take((size_t)9 * 4 * 8 * 384 * 16);
    float* sf2 = (float*)take(384 * 4);
    int* bq2 = (int*)take(384 * 4);
    signed char* wstg3 = (signed char*)take((size_t)3 * 3 * 8 * 384 * 16);
    float* sf3 = (float*)take(384 * 4);
    int* bq3 = (int*)take(384 * 4);
    signed char* wstg4 = (signed char*)take((size_t)3 * 3 * 8 * 384 * 16);
    float* sf4 = (float*)take(384 * 4);
    int* bq4 = (int*)take(384 * 4);
    signed char* n0 = (signed char*)take((size_t)64 * 289 * 384);  // int8 NHWC
    signed char* q1 = (signed char*)take((size_t)64 * 289 * 512);  // padded 512ch
    signed char* q2 = (signed char*)take((size_t)64 * 289 * 384);
    float* fbuf = (float*)take((size_t)64 * 289 * 512 * 4);        // fp32 pre-requant

    hipMemsetAsync(scal, 0, 64, stream);
    hipMemsetAsync(wstg1, 0, (size_t)1 * 3 * 8 * 512 * 16, stream);   // pad oc rows
    hipMemsetAsync(wstg2, 0, (size_t)9 * 4 * 8 * 384 * 16, stream);   // pad cin chunks

    // stage 0: quantize input
    amax_abs_kernel<<<1024, 256, 0, stream>>>(x, 64 * 384 * 289, scal + 0);
    quant_x_kernel<<<dim3(10, 12, 64), 256, 0, stream>>>(x, n0, scal);

    // conv1: 1x1, 384->448 (OC padded to 512; pads stored as 0 -> q1 pad = 0)
    prep_w_kernel<<<448, 256, 0, stream>>>(w1, g1, b1, m1, v1, scal, 0, wstg1, sf1, bq1,
                                           384, 1, 512, 3);
    qconv_mfma<384, 448, 512, 1, 1, 0, 0, 0>
        <<<dim3(145, 4), 256, 0, stream>>>(n0, wstg1, sf1, bq1, fbuf, scal + 1, zero16, 0, 0);
    requant_kernel<<<2048, 256, 0, stream>>>(fbuf, q1, scal, 1, 64 * 289 * 512 / 4);

    // conv2: 3x3 pad 1, 512(padded)->384
    prep_w_kernel<<<384, 256, 0, stream>>>(w2, g2, b2, m2, v2, scal, 1, wstg2, sf2, bq2,
                                           448, 9, 384, 4);
    qconv_mfma<512, 384, 384, 3, 3, 1, 1, 0>
        <<<dim3(145, 3), 256, 0, stream>>>(q1, wstg2, sf2, bq2, fbuf, scal + 2, zero16, 0, 0);
    requant_kernel<<<2048, 256, 0, stream>>>(fbuf, q2, scal, 2, 64 * 289 * 384 / 4);

    // branches: conv3 (1x3, pad w), conv4 (3x1, pad h) -> fp32 NCHW into d_out
    prep_w_kernel<<<384, 256, 0, stream>>>(w3, g3, b3, m3, v3, scal, 2, wstg3, sf3, bq3,
                                           384, 3, 384, 3);
    prep_w_kernel<<<384, 256, 0, stream>>>(w4, g4, b4, m4, v4, scal, 2, wstg4, sf4, bq4,
                                           384, 3, 384, 3);
    qconv_mfma<384, 384, 384, 1, 3, 0, 1, 1>
        <<<dim3(145, 3), 256, 0, stream>>>(q2, wstg3, sf3, bq3, out, scal + 3, zero16, 0, 768);
    qconv_mfma<384, 384, 384, 3, 1, 1, 0, 1>
        <<<dim3(145, 3), 256, 0, stream>>>(q2, wstg4, sf4, bq4, out, scal + 3, zero16, 384, 768);

    // final: requant concat in place
    final_requant_kernel<<<2048, 256, 0, stream>>>(out, scal, 3, 64 * 768 * 289 / 4);
}

// Round 5
// 286.286 us; speedup vs baseline: 2.1953x; 1.0272x over previous
//
#include <hip/hip_runtime.h>
#include <stdint.h>

#define NLVL 127.0f
#define NPOS (64 * 289)

typedef int v4i __attribute__((ext_vector_type(4)));
typedef int v16i __attribute__((ext_vector_type(16)));
typedef unsigned int uint;

__device__ __forceinline__ void gload_lds16(const void* g, void* l) {
    __builtin_amdgcn_global_load_lds((const __attribute__((address_space(1))) void*)g,
                                     (__attribute__((address_space(3))) void*)l, 16, 0, 0);
}

// -------- global abs-max reduction (atomicMax on float bits; values >= 0) ----
__global__ __launch_bounds__(256) void amax_abs_kernel(const float* __restrict__ x,
                                                       int n, float* __restrict__ slot) {
    __shared__ float red[256];
    float lm = 0.f;
    for (int i = blockIdx.x * 256 + threadIdx.x; i < n; i += gridDim.x * 256)
        lm = fmaxf(lm, fabsf(x[i]));
    red[threadIdx.x] = lm;
    __syncthreads();
    for (int s = 128; s > 0; s >>= 1) {
        if (threadIdx.x < s) red[threadIdx.x] = fmaxf(red[threadIdx.x], red[threadIdx.x + s]);
        __syncthreads();
    }
    if (threadIdx.x == 0) atomicMax((unsigned int*)slot, __float_as_uint(red[0]));
}

// -------- quantize input x: NCHW fp32 -> slab int8 [c16][NPOS][16] -----------
// block: 64 positions x 384 channels
__global__ __launch_bounds__(256) void quant_x_kernel(const float* __restrict__ x,
                                                      signed char* __restrict__ n0,
                                                      const float* __restrict__ scal) {
    __shared__ uint t32[64][97];
    const float s = scal[0] / NLVL;
    const int tid = threadIdx.x;
    const int pi = tid & 63;
    const int pos = blockIdx.x * 64 + pi;
    const int n = pos / 289;
    const int hw = pos - n * 289;
    const float* xb = x + (size_t)n * 384 * 289 + hw;
    for (int cq = tid >> 6; cq < 96; cq += 4) {
        uint pk = 0;
#pragma unroll
        for (int k = 0; k < 4; ++k) {
            const float f = xb[(size_t)(cq * 4 + k) * 289];
            float q = rintf(f / s);
            q = fminf(fmaxf(q, -128.f), 127.f);
            pk |= ((uint)((int)q & 0xff)) << (8 * k);
        }
        t32[pi][cq] = pk;
    }
    __syncthreads();
    for (int k = 0; k < 6; ++k) {
        const int c16 = (tid >> 6) + k * 4;  // 0..23
        uint4 v;
        v.x = t32[pi][c16 * 4 + 0];
        v.y = t32[pi][c16 * 4 + 1];
        v.z = t32[pi][c16 * 4 + 2];
        v.w = t32[pi][c16 * 4 + 3];
        *(uint4*)&n0[((size_t)c16 * NPOS + pos) * 16] = v;
    }
}

// -------- fold BN into weights, per-out-channel int8 quant, bias to int ------
// w [O][I][KH][KW] -> wstg [tap][kcn][j=8][OCP][16] int8 (128-ch chunk layout)
__global__ __launch_bounds__(256) void prep_w_kernel(
    const float* __restrict__ w, const float* __restrict__ g, const float* __restrict__ b,
    const float* __restrict__ m, const float* __restrict__ v,
    const float* __restrict__ scal, int amax_idx,
    signed char* __restrict__ wstg, float* __restrict__ conv_sf, int* __restrict__ bqi,
    int I, int KHW, int OCP, int KCN) {
    const int o = blockIdx.x;
    const int E = I * KHW;
    __shared__ float red[256];
    const float std_ = sqrtf(v[o] + 1e-5f);
    const float fac = g[o] / std_;
    float lm = 0.f;
    for (int e = threadIdx.x; e < E; e += 256)
        lm = fmaxf(lm, fabsf(w[(size_t)o * E + e] * fac));
    red[threadIdx.x] = lm;
    __syncthreads();
    for (int s = 128; s > 0; s >>= 1) {
        if (threadIdx.x < s) red[threadIdx.x] = fmaxf(red[threadIdx.x], red[threadIdx.x + s]);
        __syncthreads();
    }
    const float w_sf = red[0] / NLVL;
    for (int e = threadIdx.x; e < E; e += 256) {
        const float wf = w[(size_t)o * E + e] * fac;
        float q = rintf(wf / w_sf);
        q = fminf(fmaxf(q, -128.f), 127.f);
        const int i = e / KHW;          // cin
        const int r = e - i * KHW;      // tap = kh*KW+kw
        const int kcn = i >> 7, j = (i >> 4) & 7, byte = i & 15;
        wstg[((((size_t)r * KCN + kcn) * 8 + j) * OCP + o) * 16 + byte] = (signed char)q;
    }
    if (threadIdx.x == 0) {
        const float a_sf = scal[amax_idx] / NLVL;
        const float csf = a_sf * w_sf;
        conv_sf[o] = csf;
        const float bf = b[o] - g[o] * m[o] / std_;
        bqi[o] = (int)rintf(bf / csf);
    }
}

// -------- int8 MFMA implicit-GEMM conv, K=128 chunks, dbuf, fused epilogue ---
// xin: slab int8 [CINP/16][NPOS][16]; wstg packed as above.
// STORE_SLAB=0: yout fp32 slab [OCP/16][NPOS][16] (pads stored 0); =1: NCHW + oc_off.
template <int CINP, int COUT, int OCP, int KH, int KW, int PH, int PW, int STORE_NCHW>
__global__ __launch_bounds__(256) void qconv_mfma(
    const signed char* __restrict__ xin, const signed char* __restrict__ wstg,
    const float* __restrict__ conv_sf, const int* __restrict__ bqv,
    float* __restrict__ yout, float* __restrict__ amax_slot,
    const signed char* __restrict__ zero16, int oc_off, int oc_total) {
    constexpr int KCN = CINP / 128;
    constexpr int KHW = KH * KW;
    constexpr int NKT = KHW * KCN;
    // per buf: A [j=8][128 pos][16B] (16KB) | B [j=8][128 oc][16B] (16KB)
    __shared__ __align__(16) signed char lds[2][32768];

    const int tid = threadIdx.x;
    const int lane = tid & 63;
    const int wid = tid >> 6;
    const int l31 = lane & 31;
    const int lh = lane >> 5;
    const int half = wid >> 1;   // pos/oc half this wave stages
    const int jbase = (wid & 1) * 4;

    const int p_blk = blockIdx.x * 128;
    const int myp = p_blk + half * 64 + lane;
    const bool rowok = myp < NPOS;
    const int pc = rowok ? myp : 0;
    const int myn = pc / 289;
    const int myhw = pc - myn * 289;
    const int myh = myhw / 17;
    const int myw = myhw - myh * 17;
    const int oc_blk = blockIdx.y * 128;

    auto stage = [&](int cbuf, int kt) {
        const int tap = kt / KCN;
        const int kc = kt - tap * KCN;
        const int kh = tap / KW;
        const int kw = tap - kh * KW;
        const int ih = myh + kh - PH;
        const int iw = myw + kw - PW;
        const bool ok = rowok & ((unsigned)ih < 17u) & ((unsigned)iw < 17u);
        const int spos = myn * 289 + ih * 17 + iw;
        signed char* Al = &lds[cbuf][0];
        signed char* Bl = &lds[cbuf][16384];
        const signed char* aslab = xin + ((size_t)(kc * 8 + jbase) * NPOS + spos) * 16;
        const signed char* bslab =
            wstg + ((((size_t)(tap * KCN + kc) * 8 + jbase)) * OCP + oc_blk + half * 64 + lane) * 16;
#pragma unroll
        for (int r = 0; r < 4; ++r) {
            const int j = jbase + r;
            gload_lds16(ok ? (aslab + (size_t)r * NPOS * 16) : zero16,
                        Al + (j * 128 + half * 64) * 16);
            gload_lds16(bslab + (size_t)r * OCP * 16, Bl + (j * 128 + half * 64) * 16);
        }
    };

    v16i acc[2][2] = {};

    stage(0, 0);
    __syncthreads();
    int cur = 0;
    for (int kt = 0; kt < NKT; ++kt) {
        if (kt + 1 < NKT) stage(cur ^ 1, kt + 1);
        const signed char* Al = &lds[cur][0];
        const signed char* Bl = &lds[cur][16384];
#pragma unroll
        for (int ks = 0; ks < 4; ++ks) {
            v4i af[2], bf[2];
#pragma unroll
            for (int it = 0; it < 2; ++it)
                af[it] = *(const v4i*)(Al + (((ks * 2 + lh) * 128) + (wid >> 1) * 64 + it * 32 + l31) * 16);
#pragma unroll
            for (int jt = 0; jt < 2; ++jt)
                bf[jt] = *(const v4i*)(Bl + (((ks * 2 + lh) * 128) + (wid & 1) * 64 + jt * 32 + l31) * 16);
#pragma unroll
            for (int it = 0; it < 2; ++it)
#pragma unroll
                for (int jt = 0; jt < 2; ++jt)
                    acc[it][jt] =
                        __builtin_amdgcn_mfma_i32_32x32x32_i8(af[it], bf[jt], acc[it][jt], 0, 0, 0);
        }
        __syncthreads();
        cur ^= 1;
    }

    // epilogue: bias + relu + per-channel scale, amax, store
    float csf[2];
    int bb[2], ocv[2];
#pragma unroll
    for (int jt = 0; jt < 2; ++jt) {
        const int oc = oc_blk + (wid & 1) * 64 + jt * 32 + l31;
        ocv[jt] = oc;
        const bool real = oc < COUT;
        csf[jt] = real ? conv_sf[oc] : 0.f;
        bb[jt] = real ? bqv[oc] : 0;
    }
    float lm = 0.f;
#pragma unroll
    for (int it = 0; it < 2; ++it) {
#pragma unroll
        for (int reg = 0; reg < 16; ++reg) {
            const int prow = p_blk + (wid >> 1) * 64 + it * 32 + (reg & 3) + 8 * (reg >> 2) + 4 * lh;
            const bool pok = prow < NPOS;
#pragma unroll
            for (int jt = 0; jt < 2; ++jt) {
                int t = acc[it][jt][reg] + bb[jt];
                t = t > 0 ? t : 0;
                const float v2 = csf[jt] * (float)t;
                if (pok) {
                    lm = fmaxf(lm, v2);
                    if (STORE_NCHW) {
                        if (ocv[jt] < COUT) {
                            const int n = prow / 289;
                            const int hw = prow - n * 289;
                            yout[((size_t)(n * oc_total + oc_off + ocv[jt])) * 289 + hw] = v2;
                        }
                    } else {
                        // fp32 slab [OCP/16][NPOS][16]; pads store 0
                        yout[((size_t)(ocv[jt] >> 4) * NPOS + prow) * 16 + (ocv[jt] & 15)] = v2;
                    }
                }
            }
        }
    }
    float* red = (float*)&lds[0][0];
    red[tid] = lm;
    __syncthreads();
    for (int s = 128; s > 0; s >>= 1) {
        if (tid < s) red[tid] = fmaxf(red[tid], red[tid + s]);
        __syncthreads();
    }
    if (tid == 0) atomicMax((unsigned int*)amax_slot, __float_as_uint(red[0]));
}

// -------- requantize fp32 slab -> int8 slab (both linear) -------------------
__global__ __launch_bounds__(256) void requant_kernel(const float* __restrict__ f,
                                                      signed char* __restrict__ q,
                                                      const float* __restrict__ scal,
                                                      int idx, int nvec) {
    const float s = scal[idx] / NLVL;
    for (int i = blockIdx.x * 256 + threadIdx.x; i < nvec; i += gridDim.x * 256) {
        const float4 v = ((const float4*)f)[i];
        const int b0 = (int)fminf(fmaxf(rintf(v.x / s), -128.f), 127.f);
        const int b1 = (int)fminf(fmaxf(rintf(v.y / s), -128.f), 127.f);
        const int b2 = (int)fminf(fmaxf(rintf(v.z / s), -128.f), 127.f);
        const int b3 = (int)fminf(fmaxf(rintf(v.w / s), -128.f), 127.f);
        ((unsigned int*)q)[i] =
            (b0 & 0xff) | ((b1 & 0xff) << 8) | ((b2 & 0xff) << 16) | ((b3 & 0xff) << 24);
    }
}

// -------- final in-place requant of d_out ------------------------------------
__global__ __launch_bounds__(256) void final_requant_kernel(float* __restrict__ y,
                                                            const float* __restrict__ scal,
                                                            int idx, int nvec) {
    const float s = scal[idx] / NLVL;
    for (int i = blockIdx.x * 256 + threadIdx.x; i < nvec; i += gridDim.x * 256) {
        float4 v = ((float4*)y)[i];
        v.x = fminf(fmaxf(rintf(v.x / s), -128.f), 127.f) * s;
        v.y = fminf(fmaxf(rintf(v.y / s), -128.f), 127.f) * s;
        v.z = fminf(fmaxf(rintf(v.z / s), -128.f), 127.f) * s;
        v.w = fminf(fmaxf(rintf(v.w / s), -128.f), 127.f) * s;
        ((float4*)y)[i] = v;
    }
}

extern "C" void kernel_launch(void* const* d_in, const int* in_sizes, int n_in,
                              void* d_out, int out_size, void* d_ws, size_t ws_size,
                              hipStream_t stream) {
    const float* x  = (const float*)d_in[0];
    const float* w1 = (const float*)d_in[1];
    const float* g1 = (const float*)d_in[2];
    const float* b1 = (const float*)d_in[3];
    const float* m1 = (const float*)d_in[4];
    const float* v1 = (const float*)d_in[5];
    const float* w2 = (const float*)d_in[6];
    const float* g2 = (const float*)d_in[7];
    const float* b2 = (const float*)d_in[8];
    const float* m2 = (const float*)d_in[9];
    const float* v2 = (const float*)d_in[10];
    const float* w3 = (const float*)d_in[11];
    const float* g3 = (const float*)d_in[12];
    const float* b3 = (const float*)d_in[13];
    const float* m3 = (const float*)d_in[14];
    const float* v3 = (const float*)d_in[15];
    const float* w4 = (const float*)d_in[16];
    const float* g4 = (const float*)d_in[17];
    const float* b4 = (const float*)d_in[18];
    const float* m4 = (const float*)d_in[19];
    const float* v4 = (const float*)d_in[20];
    float* out = (float*)d_out;
    char* ws = (char*)d_ws;

    size_t off = 0;
    auto take = [&](size_t bytes) {
        char* p = ws + off;
        off = (off + bytes + 255) & ~(size_t)255;
        return p;
    };
    float* scal = (float*)take(64);  // amax slots 0..3; bytes 32..47 = zero16
    const signed char* zero16 = (const signed char*)(scal + 8);
    signed char* wstg1 = (signed char*)take((size_t)1 * 3 * 8 * 512 * 16);
    float* sf1 = (float*)take(448 * 4);
    int* bq1 = (int*)take(448 * 4);
    signed char* wstg2 = (signed char*)take((size_t)9 * 4 * 8 * 384 * 16);
    float* sf2 = (float*)take(384 * 4);
    int* bq2 = (int*)take(384 * 4);
    signed char* wstg3 = (signed char*)take((size_t)3 * 3 * 8 * 384 * 16);
    float* sf3 = (float*)take(384 * 4);
    int* bq3 = (int*)take(384 * 4);
    signed char* wstg4 = (signed char*)take((size_t)3 * 3 * 8 * 384 * 16);
    float* sf4 = (float*)take(384 * 4);
    int* bq4 = (int*)take(384 * 4);
    signed char* n0 = (signed char*)take((size_t)24 * NPOS * 16);   // slab int8 384ch
    signed char* q1 = (signed char*)take((size_t)32 * NPOS * 16);   // slab int8 512ch
    signed char* q2 = (signed char*)take((size_t)24 * NPOS * 16);   // slab int8 384ch
    float* fbuf = (float*)take((size_t)32 * NPOS * 16 * 4);         // fp32 slab

    hipMemsetAsync(scal, 0, 64, stream);
    hipMemsetAsync(wstg1, 0, (size_t)1 * 3 * 8 * 512 * 16, stream);   // pad oc rows
    hipMemsetAsync(wstg2, 0, (size_t)9 * 4 * 8 * 384 * 16, stream);   // pad cin chunks

    // stage 0: quantize input
    amax_abs_kernel<<<1024, 256, 0, stream>>>(x, 64 * 384 * 289, scal + 0);
    quant_x_kernel<<<289, 256, 0, stream>>>(x, n0, scal);

    // conv1: 1x1, 384->448 (OC padded to 512; pads stored as 0 -> q1 pad = 0)
    prep_w_kernel<<<448, 256, 0, stream>>>(w1, g1, b1, m1, v1, scal, 0, wstg1, sf1, bq1,
                                           384, 1, 512, 3);
    qconv_mfma<384, 448, 512, 1, 1, 0, 0, 0>
        <<<dim3(145, 4), 256, 0, stream>>>(n0, wstg1, sf1, bq1, fbuf, scal + 1, zero16, 0, 0);
    requant_kernel<<<2048, 256, 0, stream>>>(fbuf, q1, scal, 1, 32 * NPOS * 16 / 4);

    // conv2: 3x3 pad 1, 512(padded)->384
    prep_w_kernel<<<384, 256, 0, stream>>>(w2, g2, b2, m2, v2, scal, 1, wstg2, sf2, bq2,
                                           448, 9, 384, 4);
    qconv_mfma<512, 384, 384, 3, 3, 1, 1, 0>
        <<<dim3(145, 3), 256, 0, stream>>>(q1, wstg2, sf2, bq2, fbuf, scal + 2, zero16, 0, 0);
    requant_kernel<<<2048, 256, 0, stream>>>(fbuf, q2, scal, 2, 24 * NPOS * 16 / 4);

    // branches: conv3 (1x3, pad w), conv4 (3x1, pad h) -> fp32 NCHW into d_out
    prep_w_kernel<<<384, 256, 0, stream>>>(w3, g3, b3, m3, v3, scal, 2, wstg3, sf3, bq3,
                                           384, 3, 384, 3);
    prep_w_kernel<<<384, 256, 0, stream>>>(w4, g4, b4, m4, v4, scal, 2, wstg4, sf4, bq4,
                                           384, 3, 384, 3);
    qconv_mfma<384, 384, 384, 1, 3, 0, 1, 1>
        <<<dim3(145, 3), 256, 0, stream>>>(q2, wstg3, sf3, bq3, out, scal + 3, zero16, 0, 768);
    qconv_mfma<384, 384, 384, 3, 1, 1, 0, 1>
        <<<dim3(145, 3), 256, 0, stream>>>(q2, wstg4, sf4, bq4, out, scal + 3, zero16, 384, 768);

    // final: requant concat in place
    final_requant_kernel<<<2048, 256, 0, stream>>>(out, scal, 3, 64 * 768 * 289 / 4);
}